// Round 6
// baseline (285.391 us; speedup 1.0000x reference)
//
#include <hip/hip_runtime.h>
#include <hip/hip_fp16.h>

#define IN_CH 16
#define OUT_CH 8

#define NT 256          // threads per block
#define EPT 8           // edges per thread in k_bin
#define TILE (NT*EPT)   // 2048 edges per tile
#define NBUK 512        // allocated buckets (489 active for N=500k)
#define BSHIFT 10       // bucket = dst >> 10  (1024 nodes per bucket)
#define BNODES 1024
#define BMASK 1023
#define SRCBITS 19      // src < 2^19 (N=500000 < 524288)
#define SRCMASK 0x7FFFF
#define CAP 12288       // slots per bucket (mean 10240, +20 sigma); CAP/NT == 48
#define RPT 48          // register-cached edges per thread in k_sort

// ---- K1: tile-local counting sort of edges into coarse dst-buckets ----
// LDS ~21 KB -> 7 blocks/CU (28 waves) for latency hiding.
__global__ void __launch_bounds__(NT) k_bin(const int4* __restrict__ src4,
                                            const int4* __restrict__ dst4, int E,
                                            int* __restrict__ gcur,
                                            unsigned* __restrict__ gbuf) {
    __shared__ int hist[NBUK];
    __shared__ int lofs[NBUK];
    __shared__ int gbase[NBUK];
    __shared__ int lcur[NBUK];
    __shared__ int scn[NT];
    __shared__ unsigned stage[TILE];
    __shared__ unsigned short posb[TILE];

    int t = threadIdx.x;
    long base = (long)blockIdx.x * TILE;
    int cnt = E - (int)base;
    if (cnt > TILE) cnt = TILE;
    // E%4==0 and TILE%4==0 -> cnt is a multiple of 4

    for (int j = t; j < NBUK; j += NT) hist[j] = 0;
    __syncthreads();

    unsigned v[EPT];
    int bk[EPT];
#pragma unroll
    for (int k = 0; k < EPT / 4; k++) {
        int i4 = t + k * NT;                 // int4 index within tile
        if (4 * i4 < cnt) {
            int4 s = src4[base / 4 + i4];
            int4 d = dst4[base / 4 + i4];
            int ss[4] = {s.x, s.y, s.z, s.w};
            int dd[4] = {d.x, d.y, d.z, d.w};
#pragma unroll
            for (int j = 0; j < 4; j++) {
                int q = 4 * k + j;
                bk[q] = dd[j] >> BSHIFT;
                v[q] = ((unsigned)(dd[j] & BMASK) << SRCBITS) | (unsigned)ss[j];
                atomicAdd(&hist[bk[q]], 1);
            }
        } else {
#pragma unroll
            for (int j = 0; j < 4; j++) bk[4 * k + j] = -1;
        }
    }
    __syncthreads();

    // block exclusive scan over 512 bucket counts (2 buckets per thread)
    int a0 = hist[2 * t], a1 = hist[2 * t + 1];
    int ts = a0 + a1;
    scn[t] = ts;
    __syncthreads();
    for (int d = 1; d < NT; d <<= 1) {
        int x = scn[t];
        int y = (t >= d) ? scn[t - d] : 0;
        __syncthreads();
        scn[t] = x + y;
        __syncthreads();
    }
    int excl = scn[t] - ts;
    lofs[2 * t] = excl;
    lofs[2 * t + 1] = excl + a0;
    lcur[2 * t] = excl;
    lcur[2 * t + 1] = excl + a0;
    if (a0 > 0) gbase[2 * t] = atomicAdd(&gcur[2 * t], a0);
    if (a1 > 0) gbase[2 * t + 1] = atomicAdd(&gcur[2 * t + 1], a1);
    __syncthreads();

    // place edges into LDS staging (tile-local counting sort)
#pragma unroll
    for (int k = 0; k < EPT; k++) {
        if (bk[k] >= 0) {
            int slot = atomicAdd(&lcur[bk[k]], 1);
            stage[slot] = v[k];
            posb[slot] = (unsigned short)bk[k];
        }
    }
    __syncthreads();

    // coalesced write-out of bucket runs
#pragma unroll
    for (int k = 0; k < EPT; k++) {
        int idx = t + k * NT;
        if (idx < cnt) {
            int b2 = posb[idx];
            int off = idx - lofs[b2] + gbase[b2];
            gbuf[(size_t)b2 * CAP + off] = stage[idx];
        }
    }
}

// ---- K2: per-bucket counting sort by local dst; bucket edges cached in
//          registers across the scan (single global read). ----
__global__ void __launch_bounds__(NT) k_sort(unsigned* __restrict__ gbuf,
                                             const int* __restrict__ gcur,
                                             float* __restrict__ dinv,
                                             int* __restrict__ offs,
                                             int* __restrict__ cnts, int N) {
    __shared__ unsigned sorted[CAP];   // 48 KB
    __shared__ int hist[BNODES];       // 4 KB
    __shared__ int cur[BNODES];        // 4 KB
    __shared__ int scn[NT];            // 1 KB

    int b = blockIdx.x, t = threadIdx.x;
    int cnt = gcur[b];
    unsigned* p = gbuf + (size_t)b * CAP;

    for (int j = t; j < BNODES; j += NT) hist[j] = 0;
    __syncthreads();

    // pass 1: load into registers + histogram of local dst
    unsigned v[RPT];
#pragma unroll
    for (int k = 0; k < RPT; k++) {
        int idx = t + k * NT;
        if (idx < cnt) {
            v[k] = p[idx];
            atomicAdd(&hist[v[k] >> SRCBITS], 1);
        }
    }
    __syncthreads();

    // scan 1024 counts, 4 per thread
    int h0 = hist[4 * t], h1 = hist[4 * t + 1], h2 = hist[4 * t + 2], h3 = hist[4 * t + 3];
    int ts = h0 + h1 + h2 + h3;
    scn[t] = ts;
    __syncthreads();
    for (int d = 1; d < NT; d <<= 1) {
        int x = scn[t];
        int y = (t >= d) ? scn[t - d] : 0;
        __syncthreads();
        scn[t] = x + y;
        __syncthreads();
    }
    int e0 = scn[t] - ts;
    int e1 = e0 + h0, e2 = e1 + h1, e3 = e2 + h2;
    cur[4 * t] = e0; cur[4 * t + 1] = e1; cur[4 * t + 2] = e2; cur[4 * t + 3] = e3;

    // emit offs / cnts / dinv (4 consecutive nodes per thread, 16 B aligned)
    int nb = b << BSHIFT;
    int n0 = nb + 4 * t;
    int gofs = b * CAP;
    if (n0 + 3 < N) {
        *(int4*)(offs + n0) = make_int4(gofs + e0, gofs + e1, gofs + e2, gofs + e3);
        *(int4*)(cnts + n0) = make_int4(h0, h1, h2, h3);
        *(float4*)(dinv + n0) = make_float4(rsqrtf(1.0f + (float)h0), rsqrtf(1.0f + (float)h1),
                                            rsqrtf(1.0f + (float)h2), rsqrtf(1.0f + (float)h3));
    } else {
#pragma unroll
        for (int k = 0; k < 4; k++) {
            int n = n0 + k;
            if (n < N) {
                int hv = (k == 0) ? h0 : (k == 1) ? h1 : (k == 2) ? h2 : h3;
                int ev = (k == 0) ? e0 : (k == 1) ? e1 : (k == 2) ? e2 : e3;
                offs[n] = gofs + ev;
                cnts[n] = hv;
                dinv[n] = rsqrtf(1.0f + (float)hv);
            }
        }
    }
    __syncthreads();

    // pass 2: scatter from registers into LDS sorted[]
#pragma unroll
    for (int k = 0; k < RPT; k++) {
        int idx = t + k * NT;
        if (idx < cnt) {
            int slot = atomicAdd(&cur[v[k] >> SRCBITS], 1);
            sorted[slot] = v[k] & SRCMASK;
        }
    }
    __syncthreads();

    // pass 3: coalesced write-back
    for (int i = t; i < cnt; i += NT) p[i] = sorted[i];
}

// ---- K3: hp16 = fp16( dinv * (x @ W^T) ), one 16 B row per node ----
__global__ void __launch_bounds__(NT) k_transform(const float* __restrict__ x,
                                                  const float* __restrict__ W,
                                                  const float* __restrict__ dinv,
                                                  uint4* __restrict__ hp16, int N) {
    __shared__ float Ws[OUT_CH * IN_CH];
    int t = threadIdx.x;
    if (t < OUT_CH * IN_CH) Ws[t] = W[t];
    __syncthreads();

    int n = blockIdx.x * blockDim.x + t;
    if (n >= N) return;

    const float4* xp = (const float4*)(x + (size_t)n * IN_CH);
    float4 a0 = xp[0], a1 = xp[1], a2 = xp[2], a3 = xp[3];
    float xi[IN_CH] = {a0.x, a0.y, a0.z, a0.w, a1.x, a1.y, a1.z, a1.w,
                       a2.x, a2.y, a2.z, a2.w, a3.x, a3.y, a3.z, a3.w};

    float di = dinv[n];

    float h[OUT_CH];
#pragma unroll
    for (int o = 0; o < OUT_CH; o++) {
        float s = 0.0f;
#pragma unroll
        for (int i = 0; i < IN_CH; i++) s += xi[i] * Ws[o * IN_CH + i];
        h[o] = s * di;
    }

    union { uint4 u; __half2 h2[4]; } pk;
    pk.h2[0] = __float22half2_rn(make_float2(h[0], h[1]));
    pk.h2[1] = __float22half2_rn(make_float2(h[2], h[3]));
    pk.h2[2] = __float22half2_rn(make_float2(h[4], h[5]));
    pk.h2[3] = __float22half2_rn(make_float2(h[6], h[7]));
    hp16[n] = pk.u;
}

// ---- K4: pull gather — one thread per node, 8-deep gather pipeline ----
__device__ __forceinline__ void acc_add(float* a, uint4 g) {
    union { uint4 u; __half2 h2[4]; } pk;
    pk.u = g;
    float2 f0 = __half22float2(pk.h2[0]);
    float2 f1 = __half22float2(pk.h2[1]);
    float2 f2 = __half22float2(pk.h2[2]);
    float2 f3 = __half22float2(pk.h2[3]);
    a[0] += f0.x; a[1] += f0.y; a[2] += f1.x; a[3] += f1.y;
    a[4] += f2.x; a[5] += f2.y; a[6] += f3.x; a[7] += f3.y;
}

__global__ void __launch_bounds__(NT) k_gather(const unsigned* __restrict__ gbuf,
                                               const int* __restrict__ offs,
                                               const int* __restrict__ cnts,
                                               const uint4* __restrict__ hp16,
                                               const float* __restrict__ dinv,
                                               const float* __restrict__ bias,
                                               float* __restrict__ out, int N) {
    int n = blockIdx.x * blockDim.x + threadIdx.x;
    if (n >= N) return;

    int e = offs[n];
    int end = e + cnts[n];

    // self-loop term
    float a[OUT_CH];
    {
        union { uint4 u; __half2 h2[4]; } pk;
        pk.u = hp16[n];
        float2 f0 = __half22float2(pk.h2[0]);
        float2 f1 = __half22float2(pk.h2[1]);
        float2 f2 = __half22float2(pk.h2[2]);
        float2 f3 = __half22float2(pk.h2[3]);
        a[0] = f0.x; a[1] = f0.y; a[2] = f1.x; a[3] = f1.y;
        a[4] = f2.x; a[5] = f2.y; a[6] = f3.x; a[7] = f3.y;
    }

    // 8-deep software pipeline of gathers
    for (; e + 7 < end; e += 8) {
        unsigned s0 = gbuf[e],     s1 = gbuf[e + 1], s2 = gbuf[e + 2], s3 = gbuf[e + 3];
        unsigned s4 = gbuf[e + 4], s5 = gbuf[e + 5], s6 = gbuf[e + 6], s7 = gbuf[e + 7];
        uint4 g0 = hp16[s0];
        uint4 g1 = hp16[s1];
        uint4 g2 = hp16[s2];
        uint4 g3 = hp16[s3];
        uint4 g4 = hp16[s4];
        uint4 g5 = hp16[s5];
        uint4 g6 = hp16[s6];
        uint4 g7 = hp16[s7];
        acc_add(a, g0); acc_add(a, g1); acc_add(a, g2); acc_add(a, g3);
        acc_add(a, g4); acc_add(a, g5); acc_add(a, g6); acc_add(a, g7);
    }
    for (; e + 3 < end; e += 4) {
        unsigned s0 = gbuf[e], s1 = gbuf[e + 1], s2 = gbuf[e + 2], s3 = gbuf[e + 3];
        uint4 g0 = hp16[s0];
        uint4 g1 = hp16[s1];
        uint4 g2 = hp16[s2];
        uint4 g3 = hp16[s3];
        acc_add(a, g0); acc_add(a, g1); acc_add(a, g2); acc_add(a, g3);
    }
    for (; e < end; e++) {
        uint4 g0 = hp16[gbuf[e]];
        acc_add(a, g0);
    }

    float di = dinv[n];
    const float4* b4 = (const float4*)bias;
    float4 bb0 = b4[0], bb1 = b4[1];
    float4 o0, o1;
    o0.x = a[0] * di + bb0.x; o0.y = a[1] * di + bb0.y;
    o0.z = a[2] * di + bb0.z; o0.w = a[3] * di + bb0.w;
    o1.x = a[4] * di + bb1.x; o1.y = a[5] * di + bb1.y;
    o1.z = a[6] * di + bb1.z; o1.w = a[7] * di + bb1.w;

    float4* op = (float4*)(out + (size_t)n * OUT_CH);
    op[0] = o0;
    op[1] = o1;
}

extern "C" void kernel_launch(void* const* d_in, const int* in_sizes, int n_in,
                              void* d_out, int out_size, void* d_ws, size_t ws_size,
                              hipStream_t stream) {
    const float* x  = (const float*)d_in[0];
    const int*   ei = (const int*)d_in[1];   // [2, E] int32
    const float* W  = (const float*)d_in[2];
    const float* b  = (const float*)d_in[3];
    float* out = (float*)d_out;

    const int N = in_sizes[0] / IN_CH;
    const int E = in_sizes[1] / 2;
    const int* src = ei;
    const int* dst = ei + E;

    const int nbuckets = (N + BNODES - 1) >> BSHIFT;   // 489

    // workspace: gcur[NBUK] | dinv[N] | hp16[N]16B | gbuf[NBUK*CAP] | offs[N] | cnts[N]
    int*      gcur = (int*)d_ws;
    float*    dinv = (float*)(gcur + NBUK);
    uint4*    hp16 = (uint4*)(dinv + N);
    unsigned* gbuf = (unsigned*)(hp16 + N);
    int*      offs = (int*)(gbuf + (size_t)NBUK * CAP);
    int*      cnts = offs + N;

    const int tiles = (E + TILE - 1) / TILE;           // 2442
    dim3 blkN((N + NT - 1) / NT);

    hipMemsetAsync(gcur, 0, NBUK * sizeof(int), stream);
    k_bin<<<tiles, NT, 0, stream>>>((const int4*)src, (const int4*)dst, E, gcur, gbuf);
    k_sort<<<nbuckets, NT, 0, stream>>>(gbuf, gcur, dinv, offs, cnts, N);
    k_transform<<<blkN, NT, 0, stream>>>(x, W, dinv, hp16, N);
    k_gather<<<blkN, NT, 0, stream>>>(gbuf, offs, cnts, hp16, dinv, b, out, N);
}

// Round 7
// 230.138 us; speedup vs baseline: 1.2401x; 1.2401x over previous
//
#include <hip/hip_runtime.h>
#include <hip/hip_fp16.h>

#define IN_CH 16
#define OUT_CH 8

#define NT 256          // threads per block
#define EPT 24          // edges per thread in k_bin
#define TILE (NT*EPT)   // 6144 edges per tile
#define NBUK 512        // allocated buckets (489 active for N=500k)
#define BSHIFT 10       // bucket = dst >> 10  (1024 nodes per bucket)
#define BNODES 1024
#define BMASK 1023
#define SRCBITS 19      // src < 2^19 (N=500000 < 524288)
#define SRCMASK 0x7FFFF
#define CAP 12288       // slots per bucket (mean 10240, +20 sigma); CAP/NT == 48
#define RPT 48          // register-cached edges per thread in k_sort

// ---- K1: tile-local counting sort of edges into coarse dst-buckets ----
// LDS 43 KB -> 3 blocks/CU. Rank trick: hist atomic returns within-bucket rank,
// so no second atomic pass. gofs = gbase - lofs folds two lookups into one.
__global__ void __launch_bounds__(NT) k_bin(const int4* __restrict__ src4,
                                            const int4* __restrict__ dst4, int E,
                                            int* __restrict__ gcur,
                                            unsigned* __restrict__ gbuf) {
    __shared__ int hist[NBUK];          // 2 KB
    __shared__ int lofs[NBUK];          // 2 KB
    __shared__ int gofs[NBUK];          // 2 KB
    __shared__ int scn[NT];             // 1 KB
    __shared__ unsigned stage[TILE];    // 24 KB
    __shared__ unsigned short posb[TILE]; // 12 KB

    int t = threadIdx.x;
    long base = (long)blockIdx.x * TILE;
    int cnt = E - (int)base;
    if (cnt > TILE) cnt = TILE;
    // E%4==0 and TILE%4==0 -> cnt is a multiple of 4

    for (int j = t; j < NBUK; j += NT) hist[j] = 0;
    __syncthreads();

    unsigned v[EPT];
    int bk[EPT];
    int rk[EPT];
#pragma unroll
    for (int k = 0; k < EPT / 4; k++) {
        int i4 = t + k * NT;                 // int4 index within tile
        if (4 * i4 < cnt) {
            int4 s = src4[base / 4 + i4];
            int4 d = dst4[base / 4 + i4];
            int ss[4] = {s.x, s.y, s.z, s.w};
            int dd[4] = {d.x, d.y, d.z, d.w};
#pragma unroll
            for (int j = 0; j < 4; j++) {
                int q = 4 * k + j;
                bk[q] = dd[j] >> BSHIFT;
                v[q] = ((unsigned)(dd[j] & BMASK) << SRCBITS) | (unsigned)ss[j];
                rk[q] = atomicAdd(&hist[bk[q]], 1);   // rank = old count
            }
        } else {
#pragma unroll
            for (int j = 0; j < 4; j++) bk[4 * k + j] = -1;
        }
    }
    __syncthreads();

    // block exclusive scan over 512 bucket counts (2 buckets per thread)
    int a0 = hist[2 * t], a1 = hist[2 * t + 1];
    int ts = a0 + a1;
    scn[t] = ts;
    __syncthreads();
    for (int d = 1; d < NT; d <<= 1) {
        int x = scn[t];
        int y = (t >= d) ? scn[t - d] : 0;
        __syncthreads();
        scn[t] = x + y;
        __syncthreads();
    }
    int excl = scn[t] - ts;
    lofs[2 * t] = excl;
    lofs[2 * t + 1] = excl + a0;
    if (a0 > 0) gofs[2 * t] = atomicAdd(&gcur[2 * t], a0) - excl;
    if (a1 > 0) gofs[2 * t + 1] = atomicAdd(&gcur[2 * t + 1], a1) - (excl + a0);
    __syncthreads();

    // place edges into LDS staging at lofs[bk]+rank (no atomics)
#pragma unroll
    for (int k = 0; k < EPT; k++) {
        if (bk[k] >= 0) {
            int slot = lofs[bk[k]] + rk[k];
            stage[slot] = v[k];
            posb[slot] = (unsigned short)bk[k];
        }
    }
    __syncthreads();

    // coalesced write-out of bucket runs
#pragma unroll
    for (int k = 0; k < EPT; k++) {
        int idx = t + k * NT;
        if (idx < cnt) {
            int b2 = posb[idx];
            gbuf[(size_t)b2 * CAP + idx + gofs[b2]] = stage[idx];
        }
    }
}

// ---- K2: per-bucket counting sort by local dst (rank trick, register-cached
//          edges) + fused node transform: hp16 = fp16(dinv * (x @ W^T)). ----
__global__ void __launch_bounds__(NT) k_sort(unsigned* __restrict__ gbuf,
                                             const int* __restrict__ gcur,
                                             const float* __restrict__ x,
                                             const float* __restrict__ W,
                                             float* __restrict__ dinv,
                                             int* __restrict__ offs,
                                             int* __restrict__ cnts,
                                             uint4* __restrict__ hp16, int N) {
    __shared__ unsigned sorted[CAP];   // 48 KB
    __shared__ int hist[BNODES];       // 4 KB (counts, then start offsets)
    __shared__ int scn[NT];            // 1 KB
    __shared__ float Ws[OUT_CH * IN_CH]; // 0.5 KB

    int b = blockIdx.x, t = threadIdx.x;
    int cnt = gcur[b];
    unsigned* p = gbuf + (size_t)b * CAP;

    if (t < OUT_CH * IN_CH) Ws[t] = W[t];
    for (int j = t; j < BNODES; j += NT) hist[j] = 0;
    __syncthreads();

    // pass 1: load into registers + histogram of local dst (rank captured)
    unsigned v[RPT];
    int rk[RPT];
#pragma unroll
    for (int k = 0; k < RPT; k++) {
        int idx = t + k * NT;
        if (idx < cnt) {
            v[k] = p[idx];
            rk[k] = atomicAdd(&hist[v[k] >> SRCBITS], 1);
        }
    }
    __syncthreads();

    // scan 1024 counts, 4 per thread
    int h0 = hist[4 * t], h1 = hist[4 * t + 1], h2 = hist[4 * t + 2], h3 = hist[4 * t + 3];
    int ts = h0 + h1 + h2 + h3;
    scn[t] = ts;
    __syncthreads();
    for (int d = 1; d < NT; d <<= 1) {
        int xv = scn[t];
        int y = (t >= d) ? scn[t - d] : 0;
        __syncthreads();
        scn[t] = xv + y;
        __syncthreads();
    }
    int e0 = scn[t] - ts;
    int e1 = e0 + h0, e2 = e1 + h1, e3 = e2 + h2;
    // reuse hist as the start-offset table (only this thread reads/writes its 4 slots)
    hist[4 * t] = e0; hist[4 * t + 1] = e1; hist[4 * t + 2] = e2; hist[4 * t + 3] = e3;

    // emit offs / cnts / dinv (4 consecutive nodes per thread, 16 B aligned)
    int nb = b << BSHIFT;
    int n0 = nb + 4 * t;
    int gofs2 = b * CAP;
    float di0 = rsqrtf(1.0f + (float)h0), di1 = rsqrtf(1.0f + (float)h1);
    float di2 = rsqrtf(1.0f + (float)h2), di3 = rsqrtf(1.0f + (float)h3);
    if (n0 + 3 < N) {
        *(int4*)(offs + n0) = make_int4(gofs2 + e0, gofs2 + e1, gofs2 + e2, gofs2 + e3);
        *(int4*)(cnts + n0) = make_int4(h0, h1, h2, h3);
        *(float4*)(dinv + n0) = make_float4(di0, di1, di2, di3);
    } else {
#pragma unroll
        for (int k = 0; k < 4; k++) {
            int n = n0 + k;
            if (n < N) {
                int hv = (k == 0) ? h0 : (k == 1) ? h1 : (k == 2) ? h2 : h3;
                int ev = (k == 0) ? e0 : (k == 1) ? e1 : (k == 2) ? e2 : e3;
                float dv = (k == 0) ? di0 : (k == 1) ? di1 : (k == 2) ? di2 : di3;
                offs[n] = gofs2 + ev;
                cnts[n] = hv;
                dinv[n] = dv;
            }
        }
    }
    __syncthreads();

    // pass 2: scatter from registers into LDS sorted[] (no atomics)
#pragma unroll
    for (int k = 0; k < RPT; k++) {
        int idx = t + k * NT;
        if (idx < cnt) {
            int slot = hist[v[k] >> SRCBITS] + rk[k];
            sorted[slot] = v[k] & SRCMASK;
        }
    }
    __syncthreads();

    // pass 3: coalesced write-back
    for (int i = t; i < cnt; i += NT) p[i] = sorted[i];

    // fused transform for this block's 4*t..4*t+3 nodes (dinv in registers)
    float dis[4] = {di0, di1, di2, di3};
#pragma unroll
    for (int k = 0; k < 4; k++) {
        int n = n0 + k;
        if (n >= N) break;
        const float4* xp = (const float4*)(x + (size_t)n * IN_CH);
        float4 a0 = xp[0], a1 = xp[1], a2 = xp[2], a3 = xp[3];
        float xi[IN_CH] = {a0.x, a0.y, a0.z, a0.w, a1.x, a1.y, a1.z, a1.w,
                           a2.x, a2.y, a2.z, a2.w, a3.x, a3.y, a3.z, a3.w};
        float di = dis[k];
        float h[OUT_CH];
#pragma unroll
        for (int o = 0; o < OUT_CH; o++) {
            float s = 0.0f;
#pragma unroll
            for (int i = 0; i < IN_CH; i++) s += xi[i] * Ws[o * IN_CH + i];
            h[o] = s * di;
        }
        union { uint4 u; __half2 h2[4]; } pk;
        pk.h2[0] = __float22half2_rn(make_float2(h[0], h[1]));
        pk.h2[1] = __float22half2_rn(make_float2(h[2], h[3]));
        pk.h2[2] = __float22half2_rn(make_float2(h[4], h[5]));
        pk.h2[3] = __float22half2_rn(make_float2(h[6], h[7]));
        hp16[n] = pk.u;
    }
}

// ---- K3: pull gather — two threads per node (even/odd edges), pair-reduce ----
__device__ __forceinline__ void acc_add(float* a, uint4 g) {
    union { uint4 u; __half2 h2[4]; } pk;
    pk.u = g;
    float2 f0 = __half22float2(pk.h2[0]);
    float2 f1 = __half22float2(pk.h2[1]);
    float2 f2 = __half22float2(pk.h2[2]);
    float2 f3 = __half22float2(pk.h2[3]);
    a[0] += f0.x; a[1] += f0.y; a[2] += f1.x; a[3] += f1.y;
    a[4] += f2.x; a[5] += f2.y; a[6] += f3.x; a[7] += f3.y;
}

__global__ void __launch_bounds__(NT) k_gather(const unsigned* __restrict__ gbuf,
                                               const int* __restrict__ offs,
                                               const int* __restrict__ cnts,
                                               const uint4* __restrict__ hp16,
                                               const float* __restrict__ dinv,
                                               const float* __restrict__ bias,
                                               float* __restrict__ out, int N) {
    int tid = blockIdx.x * blockDim.x + threadIdx.x;
    int n = tid >> 1;
    if (n >= N) return;
    int q = tid & 1;

    int beg = offs[n];
    int end = beg + cnts[n];

    float a[OUT_CH] = {0, 0, 0, 0, 0, 0, 0, 0};
    if (q == 0) {
        union { uint4 u; __half2 h2[4]; } pk;
        pk.u = hp16[n];                  // self-loop term
        float2 f0 = __half22float2(pk.h2[0]);
        float2 f1 = __half22float2(pk.h2[1]);
        float2 f2 = __half22float2(pk.h2[2]);
        float2 f3 = __half22float2(pk.h2[3]);
        a[0] = f0.x; a[1] = f0.y; a[2] = f1.x; a[3] = f1.y;
        a[4] = f2.x; a[5] = f2.y; a[6] = f3.x; a[7] = f3.y;
    }

    // 4-deep pipeline over this thread's (stride-2) half of the edge list
    int e = beg + q;
    for (; e + 6 < end; e += 8) {
        unsigned s0 = gbuf[e], s1 = gbuf[e + 2], s2 = gbuf[e + 4], s3 = gbuf[e + 6];
        uint4 g0 = hp16[s0];
        uint4 g1 = hp16[s1];
        uint4 g2 = hp16[s2];
        uint4 g3 = hp16[s3];
        acc_add(a, g0); acc_add(a, g1); acc_add(a, g2); acc_add(a, g3);
    }
    for (; e < end; e += 2) {
        uint4 g0 = hp16[gbuf[e]];
        acc_add(a, g0);
    }

    // pair reduction: lane pairs (2j, 2j+1) hold the same node
#pragma unroll
    for (int c = 0; c < OUT_CH; c++) a[c] += __shfl_xor(a[c], 1);

    float di = dinv[n];
    const float4* b4 = (const float4*)bias;
    float4 bb = b4[q];
    float4 o;
    o.x = a[4 * q + 0] * di + bb.x;
    o.y = a[4 * q + 1] * di + bb.y;
    o.z = a[4 * q + 2] * di + bb.z;
    o.w = a[4 * q + 3] * di + bb.w;
    ((float4*)(out + (size_t)n * OUT_CH))[q] = o;   // 16 B per lane, coalesced
}

extern "C" void kernel_launch(void* const* d_in, const int* in_sizes, int n_in,
                              void* d_out, int out_size, void* d_ws, size_t ws_size,
                              hipStream_t stream) {
    const float* x  = (const float*)d_in[0];
    const int*   ei = (const int*)d_in[1];   // [2, E] int32
    const float* W  = (const float*)d_in[2];
    const float* b  = (const float*)d_in[3];
    float* out = (float*)d_out;

    const int N = in_sizes[0] / IN_CH;
    const int E = in_sizes[1] / 2;
    const int* src = ei;
    const int* dst = ei + E;

    const int nbuckets = (N + BNODES - 1) >> BSHIFT;   // 489

    // workspace: gcur[NBUK] | dinv[N] | hp16[N]16B | gbuf[NBUK*CAP] | offs[N] | cnts[N]
    int*      gcur = (int*)d_ws;
    float*    dinv = (float*)(gcur + NBUK);
    uint4*    hp16 = (uint4*)(dinv + N);
    unsigned* gbuf = (unsigned*)(hp16 + N);
    int*      offs = (int*)(gbuf + (size_t)NBUK * CAP);
    int*      cnts = offs + N;

    const int tiles = (E + TILE - 1) / TILE;           // 814
    dim3 blkG((2 * N + NT - 1) / NT);

    hipMemsetAsync(gcur, 0, NBUK * sizeof(int), stream);
    k_bin<<<tiles, NT, 0, stream>>>((const int4*)src, (const int4*)dst, E, gcur, gbuf);
    k_sort<<<nbuckets, NT, 0, stream>>>(gbuf, gcur, x, W, dinv, offs, cnts, hp16, N);
    k_gather<<<blkG, NT, 0, stream>>>(gbuf, offs, cnts, hp16, dinv, b, out, N);
}

// Round 8
// 222.144 us; speedup vs baseline: 1.2847x; 1.0360x over previous
//
#include <hip/hip_runtime.h>
#include <hip/hip_fp16.h>

#define IN_CH 16
#define OUT_CH 8

#define NT 256          // threads per block
#define EPT 24          // edges per thread in k_bin
#define TILE (NT*EPT)   // 6144 edges per tile
#define NBUK 512        // allocated buckets (489 active for N=500k)
#define BSHIFT 10       // bucket = dst >> 10  (1024 nodes per bucket)
#define BNODES 1024
#define BMASK 1023
#define SRCBITS 19      // src < 2^19 (N=500000 < 524288)
#define SRCMASK 0x7FFFF
#define CAP 11264       // slots per bucket (mean 10240, +10 sigma); CAP/NT == 44
#define RPT 44          // register-cached edges per thread in k_sort

// ---- K1: tile-local counting sort of edges into coarse dst-buckets ----
// LDS ~42 KB -> 3 blocks/CU. Rank trick + wave-shfl scan (1 barrier).
__global__ void __launch_bounds__(NT) k_bin(const int4* __restrict__ src4,
                                            const int4* __restrict__ dst4, int E,
                                            int* __restrict__ gcur,
                                            unsigned* __restrict__ gbuf) {
    __shared__ int hist[NBUK];          // 2 KB
    __shared__ int lofs[NBUK];          // 2 KB
    __shared__ int gofs[NBUK];          // 2 KB
    __shared__ int wsum[4];
    __shared__ unsigned stage[TILE];    // 24 KB
    __shared__ unsigned short posb[TILE]; // 12 KB

    int t = threadIdx.x;
    long base = (long)blockIdx.x * TILE;
    int cnt = E - (int)base;
    if (cnt > TILE) cnt = TILE;
    // E%4==0 and TILE%4==0 -> cnt is a multiple of 4

    for (int j = t; j < NBUK; j += NT) hist[j] = 0;
    __syncthreads();

    unsigned v[EPT];
    int bk[EPT];
    int rk[EPT];
#pragma unroll
    for (int k = 0; k < EPT / 4; k++) {
        int i4 = t + k * NT;                 // int4 index within tile
        if (4 * i4 < cnt) {
            int4 s = src4[base / 4 + i4];
            int4 d = dst4[base / 4 + i4];
            int ss[4] = {s.x, s.y, s.z, s.w};
            int dd[4] = {d.x, d.y, d.z, d.w};
#pragma unroll
            for (int j = 0; j < 4; j++) {
                int q = 4 * k + j;
                bk[q] = dd[j] >> BSHIFT;
                v[q] = ((unsigned)(dd[j] & BMASK) << SRCBITS) | (unsigned)ss[j];
                rk[q] = atomicAdd(&hist[bk[q]], 1);   // rank = old count
            }
        } else {
#pragma unroll
            for (int j = 0; j < 4; j++) bk[4 * k + j] = -1;
        }
    }
    __syncthreads();

    // exclusive scan over 512 bucket counts: wave shfl scan + wave-total combine
    int a0 = hist[2 * t], a1 = hist[2 * t + 1];
    int ts = a0 + a1;
    int lane = t & 63, wv = t >> 6;
    int inc = ts;
#pragma unroll
    for (int d = 1; d < 64; d <<= 1) {
        int y = __shfl_up(inc, d);
        if (lane >= d) inc += y;
    }
    if (lane == 63) wsum[wv] = inc;
    __syncthreads();
    int wpre = 0;
#pragma unroll
    for (int w = 0; w < 4; w++) wpre += (w < wv) ? wsum[w] : 0;
    int excl = wpre + inc - ts;

    lofs[2 * t] = excl;
    lofs[2 * t + 1] = excl + a0;
    if (a0 > 0) gofs[2 * t] = atomicAdd(&gcur[2 * t], a0) - excl;
    if (a1 > 0) gofs[2 * t + 1] = atomicAdd(&gcur[2 * t + 1], a1) - (excl + a0);
    __syncthreads();

    // place edges into LDS staging at lofs[bk]+rank (no atomics)
#pragma unroll
    for (int k = 0; k < EPT; k++) {
        if (bk[k] >= 0) {
            int slot = lofs[bk[k]] + rk[k];
            stage[slot] = v[k];
            posb[slot] = (unsigned short)bk[k];
        }
    }
    __syncthreads();

    // coalesced write-out of bucket runs
#pragma unroll
    for (int k = 0; k < EPT; k++) {
        int idx = t + k * NT;
        if (idx < cnt) {
            int b2 = posb[idx];
            gbuf[(size_t)b2 * CAP + idx + gofs[b2]] = stage[idx];
        }
    }
}

// ---- K2: per-bucket counting sort by local dst (rank trick, register-cached
//          edges, vectorized global I/O) + fused transform hp16. LDS ~49.5 KB
//          -> 3 blocks/CU. ----
__global__ void __launch_bounds__(NT) k_sort(unsigned* __restrict__ gbuf,
                                             const int* __restrict__ gcur,
                                             const float* __restrict__ x,
                                             const float* __restrict__ W,
                                             float* __restrict__ dinv,
                                             int* __restrict__ offs,
                                             int* __restrict__ cnts,
                                             uint4* __restrict__ hp16, int N) {
    __shared__ unsigned sorted[CAP];   // 44 KB
    __shared__ int hist[BNODES];       // 4 KB (counts, then start offsets)
    __shared__ int wsum[4];
    __shared__ float Ws[OUT_CH * IN_CH]; // 0.5 KB

    int b = blockIdx.x, t = threadIdx.x;
    int cnt = gcur[b];
    unsigned* p = gbuf + (size_t)b * CAP;

    if (t < OUT_CH * IN_CH) Ws[t] = W[t];
    for (int j = t; j < BNODES; j += NT) hist[j] = 0;
    __syncthreads();

    // pass 1: vectorized load into registers + histogram of local dst (rank)
    unsigned v[RPT];
    int rk[RPT];
#pragma unroll
    for (int k4 = 0; k4 < RPT / 4; k4++) {
        int idx = 4 * t + k4 * 4 * NT;       // always < CAP, in-bounds read
        uint4 vv = *(const uint4*)(p + idx);
        unsigned vs[4] = {vv.x, vv.y, vv.z, vv.w};
#pragma unroll
        for (int j = 0; j < 4; j++) {
            int k = 4 * k4 + j;
            if (idx + j < cnt) {
                v[k] = vs[j];
                rk[k] = atomicAdd(&hist[v[k] >> SRCBITS], 1);
            }
        }
    }
    __syncthreads();

    // exclusive scan over 1024 counts: wave shfl scan + wave-total combine
    int h0 = hist[4 * t], h1 = hist[4 * t + 1], h2 = hist[4 * t + 2], h3 = hist[4 * t + 3];
    int ts = h0 + h1 + h2 + h3;
    int lane = t & 63, wv = t >> 6;
    int inc = ts;
#pragma unroll
    for (int d = 1; d < 64; d <<= 1) {
        int y = __shfl_up(inc, d);
        if (lane >= d) inc += y;
    }
    if (lane == 63) wsum[wv] = inc;
    __syncthreads();
    int wpre = 0;
#pragma unroll
    for (int w = 0; w < 4; w++) wpre += (w < wv) ? wsum[w] : 0;
    int e0 = wpre + inc - ts;
    int e1 = e0 + h0, e2 = e1 + h1, e3 = e2 + h2;
    // reuse hist as the start-offset table (disjoint slots per thread)
    hist[4 * t] = e0; hist[4 * t + 1] = e1; hist[4 * t + 2] = e2; hist[4 * t + 3] = e3;

    // emit offs / cnts / dinv (4 consecutive nodes per thread, 16 B aligned)
    int nb = b << BSHIFT;
    int n0 = nb + 4 * t;
    int gofs2 = b * CAP;
    float di0 = rsqrtf(1.0f + (float)h0), di1 = rsqrtf(1.0f + (float)h1);
    float di2 = rsqrtf(1.0f + (float)h2), di3 = rsqrtf(1.0f + (float)h3);
    if (n0 + 3 < N) {
        *(int4*)(offs + n0) = make_int4(gofs2 + e0, gofs2 + e1, gofs2 + e2, gofs2 + e3);
        *(int4*)(cnts + n0) = make_int4(h0, h1, h2, h3);
        *(float4*)(dinv + n0) = make_float4(di0, di1, di2, di3);
    } else {
#pragma unroll
        for (int k = 0; k < 4; k++) {
            int n = n0 + k;
            if (n < N) {
                int hv = (k == 0) ? h0 : (k == 1) ? h1 : (k == 2) ? h2 : h3;
                int ev = (k == 0) ? e0 : (k == 1) ? e1 : (k == 2) ? e2 : e3;
                float dv = (k == 0) ? di0 : (k == 1) ? di1 : (k == 2) ? di2 : di3;
                offs[n] = gofs2 + ev;
                cnts[n] = hv;
                dinv[n] = dv;
            }
        }
    }
    __syncthreads();

    // pass 2: scatter from registers into LDS sorted[] (no atomics)
#pragma unroll
    for (int k = 0; k < RPT; k++) {
        int idx = t + (k % 4) + (k / 4) * 4 * NT;  // matches pass-1 indexing
        (void)idx;
    }
#pragma unroll
    for (int k4 = 0; k4 < RPT / 4; k4++) {
#pragma unroll
        for (int j = 0; j < 4; j++) {
            int k = 4 * k4 + j;
            int idx = 4 * t + k4 * 4 * NT + j;
            if (idx < cnt) {
                int slot = hist[v[k] >> SRCBITS] + rk[k];
                sorted[slot] = v[k] & SRCMASK;
            }
        }
    }
    __syncthreads();

    // pass 3: vectorized coalesced write-back (b128 LDS reads, int4 stores)
    int full = cnt & ~3;
    for (int i = 4 * t; i < full; i += 4 * NT) {
        uint4 sv = *(const uint4*)&sorted[i];
        *(uint4*)(p + i) = sv;
    }
    for (int i = full + t; i < cnt; i += NT) p[i] = sorted[i];

    // fused transform for this block's nodes (dinv already in registers)
    float dis[4] = {di0, di1, di2, di3};
#pragma unroll
    for (int k = 0; k < 4; k++) {
        int n = n0 + k;
        if (n >= N) break;
        const float4* xp = (const float4*)(x + (size_t)n * IN_CH);
        float4 a0 = xp[0], a1 = xp[1], a2 = xp[2], a3 = xp[3];
        float xi[IN_CH] = {a0.x, a0.y, a0.z, a0.w, a1.x, a1.y, a1.z, a1.w,
                           a2.x, a2.y, a2.z, a2.w, a3.x, a3.y, a3.z, a3.w};
        float di = dis[k];
        float h[OUT_CH];
#pragma unroll
        for (int o = 0; o < OUT_CH; o++) {
            float s = 0.0f;
#pragma unroll
            for (int i = 0; i < IN_CH; i++) s += xi[i] * Ws[o * IN_CH + i];
            h[o] = s * di;
        }
        union { uint4 u; __half2 h2[4]; } pk;
        pk.h2[0] = __float22half2_rn(make_float2(h[0], h[1]));
        pk.h2[1] = __float22half2_rn(make_float2(h[2], h[3]));
        pk.h2[2] = __float22half2_rn(make_float2(h[4], h[5]));
        pk.h2[3] = __float22half2_rn(make_float2(h[6], h[7]));
        hp16[n] = pk.u;
    }
}

// ---- K3: pull gather — four threads per node, quad shfl-reduce ----
__device__ __forceinline__ void acc_add(float* a, uint4 g) {
    union { uint4 u; __half2 h2[4]; } pk;
    pk.u = g;
    float2 f0 = __half22float2(pk.h2[0]);
    float2 f1 = __half22float2(pk.h2[1]);
    float2 f2 = __half22float2(pk.h2[2]);
    float2 f3 = __half22float2(pk.h2[3]);
    a[0] += f0.x; a[1] += f0.y; a[2] += f1.x; a[3] += f1.y;
    a[4] += f2.x; a[5] += f2.y; a[6] += f3.x; a[7] += f3.y;
}

__global__ void __launch_bounds__(NT) k_gather(const unsigned* __restrict__ gbuf,
                                               const int* __restrict__ offs,
                                               const int* __restrict__ cnts,
                                               const uint4* __restrict__ hp16,
                                               const float* __restrict__ dinv,
                                               const float* __restrict__ bias,
                                               float* __restrict__ out, int N) {
    int tid = blockIdx.x * blockDim.x + threadIdx.x;
    int n = tid >> 2;
    if (n >= N) return;
    int q = tid & 3;

    int beg = offs[n];
    int end = beg + cnts[n];

    float a[OUT_CH] = {0, 0, 0, 0, 0, 0, 0, 0};
    if (q == 0) {
        union { uint4 u; __half2 h2[4]; } pk;
        pk.u = hp16[n];                  // self-loop term
        float2 f0 = __half22float2(pk.h2[0]);
        float2 f1 = __half22float2(pk.h2[1]);
        float2 f2 = __half22float2(pk.h2[2]);
        float2 f3 = __half22float2(pk.h2[3]);
        a[0] = f0.x; a[1] = f0.y; a[2] = f1.x; a[3] = f1.y;
        a[4] = f2.x; a[5] = f2.y; a[6] = f3.x; a[7] = f3.y;
    }

    // this lane handles edges beg+q, beg+q+4, ... (2-deep pipeline)
    int e = beg + q;
    for (; e + 4 < end; e += 8) {
        unsigned s0 = gbuf[e], s1 = gbuf[e + 4];
        uint4 g0 = hp16[s0];
        uint4 g1 = hp16[s1];
        acc_add(a, g0);
        acc_add(a, g1);
    }
    if (e < end) {
        uint4 g0 = hp16[gbuf[e]];
        acc_add(a, g0);
    }

    // quad reduction: lanes 4j..4j+3 hold the same node
#pragma unroll
    for (int c = 0; c < OUT_CH; c++) {
        a[c] += __shfl_xor(a[c], 1);
        a[c] += __shfl_xor(a[c], 2);
    }

    float di = dinv[n];
    float2 o;
    o.x = a[2 * q + 0] * di + bias[2 * q + 0];
    o.y = a[2 * q + 1] * di + bias[2 * q + 1];
    ((float2*)(out + (size_t)n * OUT_CH))[q] = o;   // 8 B per lane, coalesced
}

extern "C" void kernel_launch(void* const* d_in, const int* in_sizes, int n_in,
                              void* d_out, int out_size, void* d_ws, size_t ws_size,
                              hipStream_t stream) {
    const float* x  = (const float*)d_in[0];
    const int*   ei = (const int*)d_in[1];   // [2, E] int32
    const float* W  = (const float*)d_in[2];
    const float* b  = (const float*)d_in[3];
    float* out = (float*)d_out;

    const int N = in_sizes[0] / IN_CH;
    const int E = in_sizes[1] / 2;
    const int* src = ei;
    const int* dst = ei + E;

    const int nbuckets = (N + BNODES - 1) >> BSHIFT;   // 489

    // workspace: gcur[NBUK] | dinv[N] | hp16[N]16B | gbuf[NBUK*CAP] | offs[N] | cnts[N]
    int*      gcur = (int*)d_ws;
    float*    dinv = (float*)(gcur + NBUK);
    uint4*    hp16 = (uint4*)(dinv + N);
    unsigned* gbuf = (unsigned*)(hp16 + N);
    int*      offs = (int*)(gbuf + (size_t)NBUK * CAP);
    int*      cnts = offs + N;

    const int tiles = (E + TILE - 1) / TILE;           // 814
    dim3 blkG((4 * (long)N + NT - 1) / NT);

    hipMemsetAsync(gcur, 0, NBUK * sizeof(int), stream);
    k_bin<<<tiles, NT, 0, stream>>>((const int4*)src, (const int4*)dst, E, gcur, gbuf);
    k_sort<<<nbuckets, NT, 0, stream>>>(gbuf, gcur, x, W, dinv, offs, cnts, hp16, N);
    k_gather<<<blkG, NT, 0, stream>>>(gbuf, offs, cnts, hp16, dinv, b, out, N);
}